// Round 3
// baseline (1441.366 us; speedup 1.0000x reference)
//
#include <hip/hip_runtime.h>
#include <cmath>

typedef __attribute__((ext_vector_type(4))) float f32x4;
typedef __attribute__((ext_vector_type(8))) short bf16x8;

// matrices are full 256x256 fp32 squares, strict upper zeroed
#define MSZ 65536

__device__ __forceinline__ unsigned short f2bf(float f){
  unsigned u = __float_as_uint(f);
  unsigned r = (u + 0x7FFFu + ((u >> 16) & 1u)) >> 16;
  return (unsigned short)r;
}

__global__ void k_sentinel(float* __restrict__ out){ out[0] = 123456.0f; }

// ---------------- K0: partition batch indices by label ----------------
__global__ void k0_partition(const int* __restrict__ lab, int* __restrict__ cnt, int* __restrict__ idx){
  __shared__ int lcnt0[8], lcnt1[8];
  int t = threadIdx.x;              // 512 threads, 8 waves
  int w = t >> 6, lane = t & 63;
  int l = lab[t];
  unsigned long long m0 = __ballot(l == 0);
  unsigned long long bm = (lane == 0) ? 0ull : ((1ull << lane) - 1ull);
  int r0 = __popcll(m0 & bm);
  int r1 = __popcll((~m0) & bm);
  if (lane == 0){ lcnt0[w] = __popcll(m0); lcnt1[w] = 64 - __popcll(m0); }
  __syncthreads();
  int base0 = 0, base1 = 0, n0 = 0;
  #pragma unroll
  for (int i = 0; i < 8; ++i){
    if (i < w){ base0 += lcnt0[i]; base1 += lcnt1[i]; }
    n0 += lcnt0[i];
  }
  int pos = (l == 0) ? (base0 + r0) : (n0 + base1 + r1);
  idx[pos] = t;
  if (t == 0){ cnt[0] = n0; cnt[1] = 512 - n0; }
}

// ---------------- K1: per-label means ----------------
__global__ __launch_bounds__(1024) void k1_means(const float* __restrict__ x, const int* __restrict__ lab,
                                                 const int* __restrict__ cnt, float* __restrict__ means){
  __shared__ int labs[512];
  __shared__ float part[8][256];
  int t = threadIdx.x, c = blockIdx.x;
  if (t < 512) labs[t] = lab[t];
  __syncthreads();
  int k = t & 255, bq = t >> 8;
  float s0 = 0.f, s1 = 0.f;
  const float* xc = x + (size_t)c * 256 + k;
  for (int b = bq; b < 512; b += 4){
    float v = xc[(size_t)b * 65536];
    if (labs[b] == 0) s0 += v; else s1 += v;
  }
  part[bq*2+0][k] = s0;
  part[bq*2+1][k] = s1;
  __syncthreads();
  if (t < 256){
    float m0 = part[0][t] + part[2][t] + part[4][t] + part[6][t];
    float m1 = part[1][t] + part[3][t] + part[5][t] + part[7][t];
    float n0 = (float)cnt[0], n1 = (float)cnt[1];
    means[(size_t)c * 256 + t]         = m0 / fmaxf(n0, 1.f);
    means[(size_t)(256 + c) * 256 + t] = m1 / fmaxf(n1, 1.f);
  }
}

// ---------------- K2: per-(channel,label) Gram via MFMA -> Sigma full square, upper zeroed ----------------
__global__ __launch_bounds__(512) void k2_gram(const float* __restrict__ x, const float* __restrict__ cov,
    const float* __restrict__ means, const int* __restrict__ cnt, const int* __restrict__ idx,
    float* __restrict__ sig, int c0){
  __shared__ uint4 XT4[1280];      // 256 k-rows x (4 uint4 data + 1 pad uint4)
  __shared__ float mlds[256];
  int t = threadIdx.x;
  int bid = blockIdx.x;
  int l = bid & 1, c = c0 + (bid >> 1);
  int n0 = cnt[0], n1 = cnt[1];
  int n = l ? n1 : n0;
  int start = l ? n0 : 0;
  if (t < 256) mlds[t] = means[(size_t)(l * 256 + c) * 256 + t];

  f32x4 acc[8][4];
  #pragma unroll
  for (int i = 0; i < 8; ++i)
    #pragma unroll
    for (int jn = 0; jn < 4; ++jn){ f32x4 z; z.x = 0.f; z.y = 0.f; z.z = 0.f; z.w = 0.f; acc[i][jn] = z; }

  int lane = t & 63, wav = t >> 6;
  int wr = wav >> 2, wc = wav & 3;
  int lrow = lane & 15, lhalf = lane >> 4;   // lhalf in [0,4)
  int kq = t & 255, bh = t >> 8;
  int nst = (n + 31) >> 5;

  for (int s = 0; s < nst; ++s){
    __syncthreads();
    unsigned pk[8];
    #pragma unroll
    for (int m = 0; m < 8; ++m){
      int b0 = s * 32 + bh * 16 + 2 * m;
      float v0 = 0.f, v1 = 0.f;
      if (b0 < n)     v0 = x[((size_t)idx[start + b0] * 256 + c) * 256 + kq];
      if (b0 + 1 < n) v1 = x[((size_t)idx[start + b0 + 1] * 256 + c) * 256 + kq];
      pk[m] = (unsigned)f2bf(v0) | ((unsigned)f2bf(v1) << 16);
    }
    XT4[kq * 5 + bh * 2 + 0] = make_uint4(pk[0], pk[1], pk[2], pk[3]);
    XT4[kq * 5 + bh * 2 + 1] = make_uint4(pk[4], pk[5], pk[6], pk[7]);
    __syncthreads();
    bf16x8 af[8], bfr[4];
    #pragma unroll
    for (int i = 0; i < 8; ++i){
      int T = wr * 8 + i;
      af[i] = *reinterpret_cast<const bf16x8*>(&XT4[(T * 16 + lrow) * 5 + lhalf]);
    }
    #pragma unroll
    for (int jn = 0; jn < 4; ++jn){
      int T = wc * 4 + jn;
      bfr[jn] = *reinterpret_cast<const bf16x8*>(&XT4[(T * 16 + lrow) * 5 + lhalf]);
    }
    #pragma unroll
    for (int i = 0; i < 8; ++i)
      #pragma unroll
      for (int jn = 0; jn < 4; ++jn)
        acc[i][jn] = __builtin_amdgcn_mfma_f32_16x16x32_bf16(af[i], bfr[jn], acc[i][jn], 0, 0, 0);
  }
  __syncthreads();

  float invn = 1.0f / fmaxf((float)n, 1.0f);
  float* sigm = sig + (size_t)bid * MSZ;
  #pragma unroll
  for (int i = 0; i < 8; ++i){
    int Rb = (wr * 8 + i) * 16 + lhalf * 4;
    #pragma unroll
    for (int jn = 0; jn < 4; ++jn){
      int Cc = (wc * 4 + jn) * 16 + lrow;
      #pragma unroll
      for (int r = 0; r < 4; ++r){
        int R = Rb + r;
        float v = acc[i][jn][r] * invn + cov[R * 256 + Cc] - mlds[R] * mlds[Cc];
        sigm[R * 256 + Cc] = (Cc <= R) ? v : 0.0f;   // zero strict upper
      }
    }
  }
}

// ---------------- K3a: blocked Cholesky in global, 32-col LDS panel ----------------
__global__ __launch_bounds__(256) void k3a_chol(float* __restrict__ sig, float* __restrict__ logdet, int c0){
  __shared__ float P[256 * 33];    // 33792 B
  int t = threadIdx.x;
  int bid = blockIdx.x;
  int l = bid & 1, c = c0 + (bid >> 1);
  float* A = sig + (size_t)bid * MSZ;
  float ldacc = 0.f;

  for (int kb = 0; kb < 8; ++kb){
    int j0 = kb * 32, m = 256 - j0;
    __syncthreads();   // protect P reuse
    for (int i = t; i < m * 32; i += 256){
      int r = i >> 5, cc = i & 31;
      P[r * 33 + cc] = A[(j0 + r) * 256 + j0 + cc];
    }
    __syncthreads();
    // factor 32x32 diag block (panel rows 0..31), simple sync-stepped
    for (int j = 0; j < 32; ++j){
      if (t == 0){
        float dv = sqrtf(P[j * 33 + j]);
        P[j * 33 + j] = dv;
        ldacc += logf(dv);
      }
      __syncthreads();
      if (t > j && t < 32) P[t * 33 + j] /= P[j * 33 + j];
      __syncthreads();
      if (t > j && t < 32){
        float lj = P[t * 33 + j];
        for (int cq = j + 1; cq <= t; ++cq)
          P[t * 33 + cq] -= lj * P[cq * 33 + j];
      }
      __syncthreads();
    }
    // TRSM rows 32..m-1 against diag block: thread t owns panel row t
    if (t >= 32 && t < m){
      for (int cc = 0; cc < 32; ++cc){
        float v = P[t * 33 + cc];
        for (int p = 0; p < cc; ++p)
          v -= P[cc * 33 + p] * P[t * 33 + p];
        P[t * 33 + cc] = v / P[cc * 33 + cc];
      }
    }
    __syncthreads();
    // store panel (mask upper-of-diag to preserve zeroed upper)
    for (int i = t; i < m * 32; i += 256){
      int r = i >> 5, cc = i & 31;
      if (r >= 32 || cc <= r)
        A[(j0 + r) * 256 + j0 + cc] = P[r * 33 + cc];
    }
    // rank-32 trailing update (lower triangle only), coalesced row rounds
    for (int r = 32; r < m; ++r){
      for (int cc = 32 + t; cc <= r; cc += 256){
        float dot = 0.f;
        #pragma unroll
        for (int p = 0; p < 32; ++p)
          dot += P[r * 33 + p] * P[cc * 33 + p];
        A[(j0 + r) * 256 + j0 + cc] -= dot;
      }
    }
  }
  if (t == 0) logdet[l * 256 + c] = 2.0f * ldacc;
}

// ---------------- K3b: TRSM L1 W = L0 in place, column-per-thread; trp = ||W||_F^2 ----------------
__global__ __launch_bounds__(256) void k3b_trsm(float* __restrict__ sig, float* __restrict__ trp, int c0){
  __shared__ float L1blk[32 * 256];   // 32 KB
  __shared__ float redw[4];
  int t = threadIdx.x, b = blockIdx.x;
  int lane = t & 63, wav = t >> 6;
  const float* L1 = sig + (size_t)(b * 2 + 1) * MSZ;
  float* W = sig + (size_t)(b * 2) * MSZ;     // starts as L0, becomes W
  float tracc = 0.f;

  for (int RB = 0; RB < 8; ++RB){
    int r0 = RB * 32;
    __syncthreads();
    for (int i = t; i < 32 * 256; i += 256)
      L1blk[i] = L1[(size_t)(r0 + (i >> 8)) * 256 + (i & 255)];
    __syncthreads();

    float acc[32];
    #pragma unroll
    for (int r = 0; r < 32; ++r) acc[r] = W[(size_t)(r0 + r) * 256 + t];

    for (int p = 0; p < r0; p += 8){
      float wv[8];
      #pragma unroll
      for (int q = 0; q < 8; ++q) wv[q] = W[(size_t)(p + q) * 256 + t];
      #pragma unroll
      for (int r = 0; r < 32; ++r){
        const f32x4 La = *(const f32x4*)&L1blk[r * 256 + p];
        const f32x4 Lb = *(const f32x4*)&L1blk[r * 256 + p + 4];
        acc[r] -= La.x * wv[0] + La.y * wv[1] + La.z * wv[2] + La.w * wv[3]
                + Lb.x * wv[4] + Lb.y * wv[5] + Lb.z * wv[6] + Lb.w * wv[7];
      }
    }
    // in-block forward substitution (column-private, no barriers)
    #pragma unroll
    for (int rr = 0; rr < 32; ++rr){
      float v = acc[rr];
      #pragma unroll
      for (int q = 0; q < rr; ++q)
        v -= L1blk[rr * 256 + r0 + q] * acc[q];
      v /= L1blk[rr * 256 + r0 + rr];
      acc[rr] = v;
      tracc += v * v;
      W[(size_t)(r0 + rr) * 256 + t] = v;
    }
  }
  #pragma unroll
  for (int m = 1; m < 64; m <<= 1) tracc += __shfl_xor(tracc, m);
  if (lane == 0) redw[wav] = tracc;
  __syncthreads();
  if (t == 0) trp[c0 + b] = redw[0] + redw[1] + redw[2] + redw[3];
}

// ---------------- K3c: quad = ||L1^-1 d||^2; final per-channel kl ----------------
__global__ __launch_bounds__(64) void k3c_quad(const float* __restrict__ means, const float* __restrict__ sig,
    const float* __restrict__ trp, const float* __restrict__ logdet, float* __restrict__ klp, int c0){
  __shared__ float y[256];
  int t = threadIdx.x, b = blockIdx.x;
  int c = c0 + b;
  const float* L1 = sig + (size_t)(b * 2 + 1) * MSZ;
  const float* m1p = means + (size_t)(256 + c) * 256;
  const float* m0p = means + (size_t)c * 256;

  for (int r = 0; r < 256; ++r){
    float part = 0.f;
    for (int p = t; p < r; p += 64)
      part += L1[(size_t)r * 256 + p] * y[p];
    #pragma unroll
    for (int m = 1; m < 64; m <<= 1) part += __shfl_xor(part, m);
    if (t == 0)
      y[r] = ((m1p[r] - m0p[r]) - part) / L1[(size_t)r * 256 + r];
    __syncthreads();
  }
  float q = 0.f;
  #pragma unroll
  for (int i = 0; i < 4; ++i){ float v = y[t + 64 * i]; q += v * v; }
  #pragma unroll
  for (int m = 1; m < 64; m <<= 1) q += __shfl_xor(q, m);
  if (t == 0)
    klp[c] = 0.5f * (trp[c] + q - 256.0f + logdet[256 + c] - logdet[c]);
}

// ---------------- K4: final reduce + scale ----------------
__global__ void k4_final(const float* __restrict__ klp, const int* __restrict__ cnt, float* __restrict__ out){
  __shared__ float red[256];
  int t = threadIdx.x;
  red[t] = klp[t];
  __syncthreads();
  for (int s = 128; s > 0; s >>= 1){
    if (t < s) red[t] += red[t + s];
    __syncthreads();
  }
  if (t == 0){
    float n0 = (float)cnt[0], n1 = (float)cnt[1];
    out[0] = red[0] * n0 * n1 / 256.0f / 512.0f / 512.0f;
  }
}

extern "C" void kernel_launch(void* const* d_in, const int* in_sizes, int n_in,
                              void* d_out, int out_size, void* d_ws, size_t ws_size,
                              hipStream_t stream){
  (void)in_sizes; (void)n_in; (void)out_size;
  const float* mu  = (const float*)d_in[0];
  const float* cov = (const float*)d_in[1];
  const int*   lab = (const int*)d_in[2];
  float* out = (float*)d_out;
  char* ws = (char*)d_ws;
  // ws layout (bytes):
  // means  @ 0        (524288)   trp @ 524288 (1024)   klp @ 525312 (1024)
  // logdet @ 526336   (2048)     cnt @ 528384 (8)      idx @ 528392 (2048)
  // sig    @ 1048576  (ch*2 full 256x256 fp32 squares)
  float* means  = (float*)ws;
  float* trp    = (float*)(ws + 524288);
  float* klp    = (float*)(ws + 525312);
  float* logdet = (float*)(ws + 526336);
  int*   cnt    = (int*)  (ws + 528384);
  int*   idx    = (int*)  (ws + 528392);
  float* sig    = (float*)(ws + 1048576);
  const size_t base = 1048576;

  int ch = 0;
  if      (ws_size >= base + (size_t)256 * 2 * MSZ * 4) ch = 256;
  else if (ws_size >= base + (size_t)64  * 2 * MSZ * 4) ch = 64;
  else if (ws_size >= base + (size_t)16  * 2 * MSZ * 4) ch = 16;
  else if (ws_size >= base + (size_t)4   * 2 * MSZ * 4) ch = 4;
  else if (ws_size >= base + (size_t)1   * 2 * MSZ * 4) ch = 1;
  if (ch == 0){
    k_sentinel<<<1, 1, 0, stream>>>(out);
    return;
  }

  k0_partition<<<1, 512, 0, stream>>>(lab, cnt, idx);
  k1_means<<<256, 1024, 0, stream>>>(mu, lab, cnt, means);
  for (int c0 = 0; c0 < 256; c0 += ch){
    k2_gram<<<ch * 2, 512, 0, stream>>>(mu, cov, means, cnt, idx, sig, c0);
    k3a_chol<<<ch * 2, 256, 0, stream>>>(sig, logdet, c0);
    k3b_trsm<<<ch, 256, 0, stream>>>(sig, trp, c0);
    k3c_quad<<<ch, 64, 0, stream>>>(means, sig, trp, logdet, klp, c0);
  }
  k4_final<<<1, 256, 0, stream>>>(klp, cnt, out);
}

// Round 4
// 1183.357 us; speedup vs baseline: 1.2180x; 1.2180x over previous
//
#include <hip/hip_runtime.h>
#include <cmath>

typedef __attribute__((ext_vector_type(4))) float f32x4;
typedef __attribute__((ext_vector_type(8))) short bf16x8;

// matrices are full 256x256 fp32 squares, strict upper zeroed
#define MSZ 65536

__device__ __forceinline__ unsigned short f2bf(float f){
  unsigned u = __float_as_uint(f);
  unsigned r = (u + 0x7FFFu + ((u >> 16) & 1u)) >> 16;
  return (unsigned short)r;
}

__global__ void k_sentinel(float* __restrict__ out){ out[0] = 123456.0f; }

// ---------------- K0: partition batch indices by label ----------------
__global__ void k0_partition(const int* __restrict__ lab, int* __restrict__ cnt, int* __restrict__ idx){
  __shared__ int lcnt0[8], lcnt1[8];
  int t = threadIdx.x;              // 512 threads, 8 waves
  int w = t >> 6, lane = t & 63;
  int l = lab[t];
  unsigned long long m0 = __ballot(l == 0);
  unsigned long long bm = (lane == 0) ? 0ull : ((1ull << lane) - 1ull);
  int r0 = __popcll(m0 & bm);
  int r1 = __popcll((~m0) & bm);
  if (lane == 0){ lcnt0[w] = __popcll(m0); lcnt1[w] = 64 - __popcll(m0); }
  __syncthreads();
  int base0 = 0, base1 = 0, n0 = 0;
  #pragma unroll
  for (int i = 0; i < 8; ++i){
    if (i < w){ base0 += lcnt0[i]; base1 += lcnt1[i]; }
    n0 += lcnt0[i];
  }
  int pos = (l == 0) ? (base0 + r0) : (n0 + base1 + r1);
  idx[pos] = t;
  if (t == 0){ cnt[0] = n0; cnt[1] = 512 - n0; }
}

// ---------------- K1: per-label means ----------------
__global__ __launch_bounds__(1024) void k1_means(const float* __restrict__ x, const int* __restrict__ lab,
                                                 const int* __restrict__ cnt, float* __restrict__ means){
  __shared__ int labs[512];
  __shared__ float part[8][256];
  int t = threadIdx.x, c = blockIdx.x;
  if (t < 512) labs[t] = lab[t];
  __syncthreads();
  int k = t & 255, bq = t >> 8;
  float s0 = 0.f, s1 = 0.f;
  const float* xc = x + (size_t)c * 256 + k;
  for (int b = bq; b < 512; b += 4){
    float v = xc[(size_t)b * 65536];
    if (labs[b] == 0) s0 += v; else s1 += v;
  }
  part[bq*2+0][k] = s0;
  part[bq*2+1][k] = s1;
  __syncthreads();
  if (t < 256){
    float m0 = part[0][t] + part[2][t] + part[4][t] + part[6][t];
    float m1 = part[1][t] + part[3][t] + part[5][t] + part[7][t];
    float n0 = (float)cnt[0], n1 = (float)cnt[1];
    means[(size_t)c * 256 + t]         = m0 / fmaxf(n0, 1.f);
    means[(size_t)(256 + c) * 256 + t] = m1 / fmaxf(n1, 1.f);
  }
}

// ---------------- K2: per-(channel,label) Gram via MFMA -> Sigma full square, upper zeroed ----------------
__global__ __launch_bounds__(512) void k2_gram(const float* __restrict__ x, const float* __restrict__ cov,
    const float* __restrict__ means, const int* __restrict__ cnt, const int* __restrict__ idx,
    float* __restrict__ sig, int c0){
  __shared__ uint4 XT4[1280];      // 256 k-rows x (4 uint4 data + 1 pad uint4)
  __shared__ float mlds[256];
  int t = threadIdx.x;
  int bid = blockIdx.x;
  int l = bid & 1, c = c0 + (bid >> 1);
  int n0 = cnt[0], n1 = cnt[1];
  int n = l ? n1 : n0;
  int start = l ? n0 : 0;
  if (t < 256) mlds[t] = means[(size_t)(l * 256 + c) * 256 + t];

  f32x4 acc[8][4];
  #pragma unroll
  for (int i = 0; i < 8; ++i)
    #pragma unroll
    for (int jn = 0; jn < 4; ++jn){ f32x4 z; z.x = 0.f; z.y = 0.f; z.z = 0.f; z.w = 0.f; acc[i][jn] = z; }

  int lane = t & 63, wav = t >> 6;
  int wr = wav >> 2, wc = wav & 3;
  int lrow = lane & 15, lhalf = lane >> 4;   // lhalf in [0,4)
  int kq = t & 255, bh = t >> 8;
  int nst = (n + 31) >> 5;

  for (int s = 0; s < nst; ++s){
    __syncthreads();
    unsigned pk[8];
    #pragma unroll
    for (int m = 0; m < 8; ++m){
      int b0 = s * 32 + bh * 16 + 2 * m;
      float v0 = 0.f, v1 = 0.f;
      if (b0 < n)     v0 = x[((size_t)idx[start + b0] * 256 + c) * 256 + kq];
      if (b0 + 1 < n) v1 = x[((size_t)idx[start + b0 + 1] * 256 + c) * 256 + kq];
      pk[m] = (unsigned)f2bf(v0) | ((unsigned)f2bf(v1) << 16);
    }
    XT4[kq * 5 + bh * 2 + 0] = make_uint4(pk[0], pk[1], pk[2], pk[3]);
    XT4[kq * 5 + bh * 2 + 1] = make_uint4(pk[4], pk[5], pk[6], pk[7]);
    __syncthreads();
    bf16x8 af[8], bfr[4];
    #pragma unroll
    for (int i = 0; i < 8; ++i){
      int T = wr * 8 + i;
      af[i] = *reinterpret_cast<const bf16x8*>(&XT4[(T * 16 + lrow) * 5 + lhalf]);
    }
    #pragma unroll
    for (int jn = 0; jn < 4; ++jn){
      int T = wc * 4 + jn;
      bfr[jn] = *reinterpret_cast<const bf16x8*>(&XT4[(T * 16 + lrow) * 5 + lhalf]);
    }
    #pragma unroll
    for (int i = 0; i < 8; ++i)
      #pragma unroll
      for (int jn = 0; jn < 4; ++jn)
        acc[i][jn] = __builtin_amdgcn_mfma_f32_16x16x32_bf16(af[i], bfr[jn], acc[i][jn], 0, 0, 0);
  }
  __syncthreads();

  float invn = 1.0f / fmaxf((float)n, 1.0f);
  float* sigm = sig + (size_t)bid * MSZ;
  #pragma unroll
  for (int i = 0; i < 8; ++i){
    int Rb = (wr * 8 + i) * 16 + lhalf * 4;
    #pragma unroll
    for (int jn = 0; jn < 4; ++jn){
      int Cc = (wc * 4 + jn) * 16 + lrow;
      #pragma unroll
      for (int r = 0; r < 4; ++r){
        int R = Rb + r;
        float v = acc[i][jn][r] * invn + cov[R * 256 + Cc] - mlds[R] * mlds[Cc];
        sigm[R * 256 + Cc] = (Cc <= R) ? v : 0.0f;   // zero strict upper
      }
    }
  }
}

// ---------------- K3a: blocked Cholesky, 512 threads, tiled trailing update ----------------
// diag: wave0-lockstep (no barriers inside). trailing: 4x4 tiles, f32x4 global RMW.
__global__ __launch_bounds__(512) void k3a_chol(float* __restrict__ sig, float* __restrict__ logdet, int c0){
  __shared__ float P[256 * 33 + 8];    // 33824 B, stride 33 (2-way bank alias only)
  int t = threadIdx.x;
  int bid = blockIdx.x;
  int l = bid & 1, c = c0 + (bid >> 1);
  float* A = sig + (size_t)bid * MSZ;
  float ldacc = 0.f;   // lane 0 of wave 0 accumulates

  for (int kb = 0; kb < 8; ++kb){
    int j0 = kb * 32, m = 256 - j0;
    __syncthreads();   // P reuse + visibility of last iter's trailing RMW
    // load 32-wide strip
    for (int i = t; i < m * 32; i += 512){
      int r = i >> 5, cc = i & 31;
      P[r * 33 + cc] = A[(size_t)(j0 + r) * 256 + j0 + cc];
    }
    __syncthreads();
    // ---- factor 32x32 diag block: wave0 lockstep, LDS-direct
    if (t < 32){
      for (int jj = 0; jj < 32; ++jj){
        float dv = sqrtf(P[jj * 33 + jj]);
        float inv = 1.0f / dv;
        if (t == 0) ldacc += logf(dv);
        if (t == jj) P[jj * 33 + jj] = dv;
        if (t > jj){
          float lv = P[t * 33 + jj] * inv;
          P[t * 33 + jj] = lv;                       // lockstep: all lanes scale first
          for (int cq = jj + 1; cq <= t; ++cq)       // then read scaled column
            P[t * 33 + cq] -= lv * P[cq * 33 + jj];
        }
      }
    }
    __syncthreads();
    // ---- TRSM rows 32..m-1 against diag block (row t per thread)
    if (t >= 32 && t < m){
      for (int cc = 0; cc < 32; ++cc){
        float v = P[t * 33 + cc];
        for (int p = 0; p < cc; ++p)
          v -= P[cc * 33 + p] * P[t * 33 + p];
        P[t * 33 + cc] = v / P[cc * 33 + cc];
      }
    }
    __syncthreads();
    // ---- store panel (preserve zeroed strict upper of diag block)
    for (int i = t; i < m * 32; i += 512){
      int r = i >> 5, cc = i & 31;
      if (r >= 32 || cc <= r)
        A[(size_t)(j0 + r) * 256 + j0 + cc] = P[r * 33 + cc];
    }
    // ---- trailing rank-32 update: 4x4 tiles over block-lower-triangle
    int m2 = m - 32;
    if (m2 > 0){
      int nt4 = m2 >> 2;
      int T = (nt4 * (nt4 + 1)) >> 1;
      for (int i = t; i < T; i += 512){
        int R = (int)((sqrtf(8.0f * (float)i + 1.0f) - 1.0f) * 0.5f);
        while ((R + 1) * (R + 2) / 2 <= i) ++R;
        while (R * (R + 1) / 2 > i) --R;
        int C = i - ((R * (R + 1)) >> 1);
        int rb = 32 + (R << 2), cb = 32 + (C << 2);
        float s00=0.f,s01=0.f,s02=0.f,s03=0.f,
              s10=0.f,s11=0.f,s12=0.f,s13=0.f,
              s20=0.f,s21=0.f,s22=0.f,s23=0.f,
              s30=0.f,s31=0.f,s32=0.f,s33=0.f;
        const float* Pr0 = &P[(rb + 0) * 33];
        const float* Pr1 = &P[(rb + 1) * 33];
        const float* Pr2 = &P[(rb + 2) * 33];
        const float* Pr3 = &P[(rb + 3) * 33];
        const float* Pc0 = &P[(cb + 0) * 33];
        const float* Pc1 = &P[(cb + 1) * 33];
        const float* Pc2 = &P[(cb + 2) * 33];
        const float* Pc3 = &P[(cb + 3) * 33];
        #pragma unroll 4
        for (int p = 0; p < 32; ++p){
          float a0 = Pr0[p], a1 = Pr1[p], a2 = Pr2[p], a3 = Pr3[p];
          float b0 = Pc0[p], b1 = Pc1[p], b2 = Pc2[p], b3 = Pc3[p];
          s00 += a0*b0; s01 += a0*b1; s02 += a0*b2; s03 += a0*b3;
          s10 += a1*b0; s11 += a1*b1; s12 += a1*b2; s13 += a1*b3;
          s20 += a2*b0; s21 += a2*b1; s22 += a2*b2; s23 += a2*b3;
          s30 += a3*b0; s31 += a3*b1; s32 += a3*b2; s33 += a3*b3;
        }
        float* Ap = &A[(size_t)(j0 + rb) * 256 + j0 + cb];
        if (R != C){
          f32x4 v0 = *(const f32x4*)&Ap[0];
          f32x4 v1 = *(const f32x4*)&Ap[256];
          f32x4 v2 = *(const f32x4*)&Ap[512];
          f32x4 v3 = *(const f32x4*)&Ap[768];
          v0.x -= s00; v0.y -= s01; v0.z -= s02; v0.w -= s03;
          v1.x -= s10; v1.y -= s11; v1.z -= s12; v1.w -= s13;
          v2.x -= s20; v2.y -= s21; v2.z -= s22; v2.w -= s23;
          v3.x -= s30; v3.y -= s31; v3.z -= s32; v3.w -= s33;
          *(f32x4*)&Ap[0]   = v0;
          *(f32x4*)&Ap[256] = v1;
          *(f32x4*)&Ap[512] = v2;
          *(f32x4*)&Ap[768] = v3;
        } else {
          Ap[0]   -= s00;
          Ap[256] -= s10; Ap[257] -= s11;
          Ap[512] -= s20; Ap[513] -= s21; Ap[514] -= s22;
          Ap[768] -= s30; Ap[769] -= s31; Ap[770] -= s32; Ap[771] -= s33;
        }
      }
    }
  }
  if (t == 0) logdet[l * 256 + c] = 2.0f * ldacc;
}

// ---------------- K3b: TRSM L1 W = L0 in place, column-per-thread; trp = ||W||_F^2 ----------------
__global__ __launch_bounds__(256) void k3b_trsm(float* __restrict__ sig, float* __restrict__ trp, int c0){
  __shared__ float L1blk[32 * 256];   // 32 KB
  __shared__ float redw[4];
  int t = threadIdx.x, b = blockIdx.x;
  int lane = t & 63, wav = t >> 6;
  const float* L1 = sig + (size_t)(b * 2 + 1) * MSZ;
  float* W = sig + (size_t)(b * 2) * MSZ;     // starts as L0, becomes W
  float tracc = 0.f;

  for (int RB = 0; RB < 8; ++RB){
    int r0 = RB * 32;
    __syncthreads();
    for (int i = t; i < 32 * 256; i += 256)
      L1blk[i] = L1[(size_t)(r0 + (i >> 8)) * 256 + (i & 255)];
    __syncthreads();

    float acc[32];
    #pragma unroll
    for (int r = 0; r < 32; ++r) acc[r] = W[(size_t)(r0 + r) * 256 + t];

    for (int p = 0; p < r0; p += 8){
      float wv[8];
      #pragma unroll
      for (int q = 0; q < 8; ++q) wv[q] = W[(size_t)(p + q) * 256 + t];
      #pragma unroll
      for (int r = 0; r < 32; ++r){
        const f32x4 La = *(const f32x4*)&L1blk[r * 256 + p];
        const f32x4 Lb = *(const f32x4*)&L1blk[r * 256 + p + 4];
        acc[r] -= La.x * wv[0] + La.y * wv[1] + La.z * wv[2] + La.w * wv[3]
                + Lb.x * wv[4] + Lb.y * wv[5] + Lb.z * wv[6] + Lb.w * wv[7];
      }
    }
    // in-block forward substitution (column-private, no barriers)
    #pragma unroll
    for (int rr = 0; rr < 32; ++rr){
      float v = acc[rr];
      #pragma unroll
      for (int q = 0; q < rr; ++q)
        v -= L1blk[rr * 256 + r0 + q] * acc[q];
      v /= L1blk[rr * 256 + r0 + rr];
      acc[rr] = v;
      tracc += v * v;
      W[(size_t)(r0 + rr) * 256 + t] = v;
    }
  }
  #pragma unroll
  for (int m = 1; m < 64; m <<= 1) tracc += __shfl_xor(tracc, m);
  if (lane == 0) redw[wav] = tracc;
  __syncthreads();
  if (t == 0) trp[c0 + b] = redw[0] + redw[1] + redw[2] + redw[3];
}

// ---------------- K3c: quad = ||L1^-1 d||^2; final per-channel kl ----------------
__global__ __launch_bounds__(64) void k3c_quad(const float* __restrict__ means, const float* __restrict__ sig,
    const float* __restrict__ trp, const float* __restrict__ logdet, float* __restrict__ klp, int c0){
  __shared__ float y[256];
  int t = threadIdx.x, b = blockIdx.x;
  int c = c0 + b;
  const float* L1 = sig + (size_t)(b * 2 + 1) * MSZ;
  const float* m1p = means + (size_t)(256 + c) * 256;
  const float* m0p = means + (size_t)c * 256;

  for (int r = 0; r < 256; ++r){
    float part = 0.f;
    for (int p = t; p < r; p += 64)
      part += L1[(size_t)r * 256 + p] * y[p];
    #pragma unroll
    for (int m = 1; m < 64; m <<= 1) part += __shfl_xor(part, m);
    if (t == 0)
      y[r] = ((m1p[r] - m0p[r]) - part) / L1[(size_t)r * 256 + r];
    __syncthreads();
  }
  float q = 0.f;
  #pragma unroll
  for (int i = 0; i < 4; ++i){ float v = y[t + 64 * i]; q += v * v; }
  #pragma unroll
  for (int m = 1; m < 64; m <<= 1) q += __shfl_xor(q, m);
  if (t == 0)
    klp[c] = 0.5f * (trp[c] + q - 256.0f + logdet[256 + c] - logdet[c]);
}

// ---------------- K4: final reduce + scale ----------------
__global__ void k4_final(const float* __restrict__ klp, const int* __restrict__ cnt, float* __restrict__ out){
  __shared__ float red[256];
  int t = threadIdx.x;
  red[t] = klp[t];
  __syncthreads();
  for (int s = 128; s > 0; s >>= 1){
    if (t < s) red[t] += red[t + s];
    __syncthreads();
  }
  if (t == 0){
    float n0 = (float)cnt[0], n1 = (float)cnt[1];
    out[0] = red[0] * n0 * n1 / 256.0f / 512.0f / 512.0f;
  }
}

extern "C" void kernel_launch(void* const* d_in, const int* in_sizes, int n_in,
                              void* d_out, int out_size, void* d_ws, size_t ws_size,
                              hipStream_t stream){
  (void)in_sizes; (void)n_in; (void)out_size;
  const float* mu  = (const float*)d_in[0];
  const float* cov = (const float*)d_in[1];
  const int*   lab = (const int*)d_in[2];
  float* out = (float*)d_out;
  char* ws = (char*)d_ws;
  // ws layout (bytes):
  // means  @ 0        (524288)   trp @ 524288 (1024)   klp @ 525312 (1024)
  // logdet @ 526336   (2048)     cnt @ 528384 (8)      idx @ 528392 (2048)
  // sig    @ 1048576  (ch*2 full 256x256 fp32 squares)
  float* means  = (float*)ws;
  float* trp    = (float*)(ws + 524288);
  float* klp    = (float*)(ws + 525312);
  float* logdet = (float*)(ws + 526336);
  int*   cnt    = (int*)  (ws + 528384);
  int*   idx    = (int*)  (ws + 528392);
  float* sig    = (float*)(ws + 1048576);
  const size_t base = 1048576;

  int ch = 0;
  if      (ws_size >= base + (size_t)256 * 2 * MSZ * 4) ch = 256;
  else if (ws_size >= base + (size_t)64  * 2 * MSZ * 4) ch = 64;
  else if (ws_size >= base + (size_t)16  * 2 * MSZ * 4) ch = 16;
  else if (ws_size >= base + (size_t)4   * 2 * MSZ * 4) ch = 4;
  else if (ws_size >= base + (size_t)1   * 2 * MSZ * 4) ch = 1;
  if (ch == 0){
    k_sentinel<<<1, 1, 0, stream>>>(out);
    return;
  }

  k0_partition<<<1, 512, 0, stream>>>(lab, cnt, idx);
  k1_means<<<256, 1024, 0, stream>>>(mu, lab, cnt, means);
  for (int c0 = 0; c0 < 256; c0 += ch){
    k2_gram<<<ch * 2, 512, 0, stream>>>(mu, cov, means, cnt, idx, sig, c0);
    k3a_chol<<<ch * 2, 512, 0, stream>>>(sig, logdet, c0);
    k3b_trsm<<<ch, 256, 0, stream>>>(sig, trp, c0);
    k3c_quad<<<ch, 64, 0, stream>>>(means, sig, trp, logdet, klp, c0);
  }
  k4_final<<<1, 256, 0, stream>>>(klp, cnt, out);
}